// Round 2
// baseline (765.915 us; speedup 1.0000x reference)
//
#include <hip/hip_runtime.h>
#include <stdint.h>

#pragma clang fp contract(off)

#define BATCH 8
#define G 64
#define P 2000
#define N 2064        // G + P
#define NW 33         // ceil(N/64) 64-bit words per mask row
#define MAXI 320
#define NMS_THR 0.3f

// ---------------- Kernel 1: stable descending rank + gather sorted boxes ----
// One block per image. Replicates jnp.argsort(-scores) (stable) exactly:
// rank(i) = #{ j : s[j] > s[i]  ||  (s[j] == s[i] && j < i) }
__global__ __launch_bounds__(256) void k_rank(
    const float* __restrict__ gt_classes,   // scores for first G (==1.0)
    const float* __restrict__ prop_scores,
    const float* __restrict__ gt_boxes,
    const float* __restrict__ prop_boxes,
    int* __restrict__ order_g,              // [B][N] sorted-pos -> orig idx
    float* __restrict__ boxes_sorted)       // [B][N][4]
{
    __shared__ float s[N];
    __shared__ int ord[N];
    const int b = blockIdx.x, tid = threadIdx.x;

    for (int i = tid; i < N; i += 256)
        s[i] = (i < G) ? gt_classes[b * G + i] : prop_scores[b * P + (i - G)];
    __syncthreads();

    for (int i = tid; i < N; i += 256) {
        const float my = s[i];
        int rank = 0;
        for (int j = 0; j < N; ++j) {
            const float sj = s[j];
            rank += (sj > my) || (sj == my && j < i);
        }
        ord[rank] = i;
    }
    __syncthreads();

    for (int i = tid; i < N; i += 256) {
        const int o = ord[i];
        order_g[b * N + i] = o;
        const float* src = (o < G) ? &gt_boxes[(size_t)(b * G + o) * 4]
                                   : &prop_boxes[(size_t)(b * P + (o - G)) * 4];
        const float4 bx = *reinterpret_cast<const float4*>(src);
        reinterpret_cast<float4*>(boxes_sorted)[(size_t)b * N + i] = bx;
    }
}

// ---------------- Kernel 2: suppression bitmask --------------------------
// grid (row_blocks=NW, col_blocks=NW, B), 64 threads. Thread t handles sorted
// row i = rb*64+t; emits u64 word: bit jj set iff j=cb*64+jj > i and IoU>thr.
__global__ __launch_bounds__(64) void k_mask(
    const float4* __restrict__ boxes_sorted,
    unsigned long long* __restrict__ mask)   // [B][N][NW]
{
    const int rb = blockIdx.x, cb = blockIdx.y, b = blockIdx.z;
    const int t = threadIdx.x;
    const int i = rb * 64 + t;

    if (cb < rb) {               // every col j <= every row i here -> all zero
        if (i < N) mask[((size_t)b * N + i) * NW + cb] = 0ull;
        return;
    }

    __shared__ float4 cbox[64];
    const int j0 = cb * 64;
    if (j0 + t < N) cbox[t] = boxes_sorted[(size_t)b * N + j0 + t];
    __syncthreads();
    if (i >= N) return;

    const float4 a = boxes_sorted[(size_t)b * N + i];
    const float areaA = (a.z - a.x) * (a.w - a.y);

    unsigned long long bits = 0ull;
    const int jmax = min(64, N - j0);
    for (int jj = 0; jj < jmax; ++jj) {
        const int j = j0 + jj;
        if (j <= i) continue;
        const float4 c = cbox[jj];
        const float areaB = (c.z - c.x) * (c.w - c.y);
        const float xx1 = fmaxf(a.x, c.x), yy1 = fmaxf(a.y, c.y);
        const float xx2 = fminf(a.z, c.z), yy2 = fminf(a.w, c.w);
        const float inter = fmaxf(xx2 - xx1, 0.0f) * fmaxf(yy2 - yy1, 0.0f);
        const float uni = areaA + areaB - inter;
        const float iou = inter / fmaxf(uni, 1e-9f);
        if (iou > NMS_THR) bits |= 1ull << jj;
    }
    mask[((size_t)b * N + i) * NW + cb] = bits;
}

// ---------------- Kernel 3: greedy scan + select + write ------------------
// One block (256 thr) per image.
__global__ __launch_bounds__(256) void k_scan(
    const unsigned long long* __restrict__ mask,
    const int* __restrict__ order_g,
    const float* __restrict__ cls_prop,
    const float* __restrict__ gt_classes,
    const float* __restrict__ prop_boxes,
    const float* __restrict__ gt_boxes,
    const float* __restrict__ prop_scores,
    float* __restrict__ out_cls, float* __restrict__ out_box,
    float* __restrict__ out_score)
{
    __shared__ unsigned long long chunk[64][NW];    // 16.9 KB
    __shared__ unsigned long long keep_words[NW];
    __shared__ unsigned char keep_orig[N];
    __shared__ int partial[256];
    __shared__ int excl[256];
    __shared__ int total;

    const int b = blockIdx.x, tid = threadIdx.x;

    unsigned long long remv = 0ull;   // wave0: lane w (<NW) owns removed-word w
    for (int c = 0; c < NW; ++c) {
        for (int k = tid; k < 64 * NW; k += 256) {
            const int r = k / NW, w = k % NW;
            const int i = c * 64 + r;
            chunk[r][w] = (i < N) ? mask[((size_t)b * N + i) * NW + w] : 0ull;
        }
        __syncthreads();
        if (tid < 64) {
            unsigned long long keepw = 0ull;
            const int rmax = min(64, N - c * 64);
            for (int r = 0; r < rmax; ++r) {
                int rem_bit = (int)((remv >> r) & 1ull);  // lane c's value is truth
                rem_bit = __shfl(rem_bit, c, 64);
                if (!rem_bit) {
                    keepw |= 1ull << r;
                    if (tid < NW) remv |= chunk[r][tid];
                }
            }
            if (tid == 0) keep_words[c] = keepw;
        }
        __syncthreads();
    }

    // scatter keep bits back to original index order
    for (int i = tid; i < N; i += 256) {
        const int o = order_g[b * N + i];
        keep_orig[o] = (unsigned char)((keep_words[i >> 6] >> (i & 63)) & 1ull);
    }
    __syncthreads();

    // block prefix sum over keep_orig
    const int SEG = (N + 255) / 256;   // 9
    const int s0 = tid * SEG;
    int sum = 0;
    for (int k = 0; k < SEG; ++k) {
        const int n = s0 + k;
        if (n < N) sum += keep_orig[n];
    }
    partial[tid] = sum;
    __syncthreads();
    if (tid == 0) {
        int run = 0;
        for (int t = 0; t < 256; ++t) { excl[t] = run; run += partial[t]; }
        total = run;
    }
    __syncthreads();

    int run = excl[tid];
    for (int k = 0; k < SEG; ++k) {
        const int n = s0 + k;
        if (n < N && keep_orig[n]) {
            const int pos = run++;
            if (pos < MAXI) {
                float cls, sc; float4 bx;
                if (n < G) {
                    cls = gt_classes[b * G + n];
                    sc  = cls;   // score_all uses gt_classes for first G
                    bx  = *reinterpret_cast<const float4*>(&gt_boxes[(size_t)(b * G + n) * 4]);
                } else {
                    const int q = n - G;
                    cls = cls_prop[b * P + q];
                    sc  = prop_scores[b * P + q];
                    bx  = *reinterpret_cast<const float4*>(&prop_boxes[(size_t)(b * P + q) * 4]);
                }
                out_cls[b * MAXI + pos] = cls;
                out_score[b * MAXI + pos] = sc;
                *reinterpret_cast<float4*>(&out_box[(size_t)(b * MAXI + pos) * 4]) = bx;
            }
        }
    }
    __syncthreads();

    // zero the invalid tail (harness poisons d_out before timed replays)
    const int cnt = min(total, MAXI);
    for (int k = cnt + tid; k < MAXI; k += 256) {
        out_cls[b * MAXI + k] = 0.0f;
        out_score[b * MAXI + k] = 0.0f;
        *reinterpret_cast<float4*>(&out_box[(size_t)(b * MAXI + k) * 4]) =
            make_float4(0.0f, 0.0f, 0.0f, 0.0f);
    }
}

extern "C" void kernel_launch(void* const* d_in, const int* in_sizes, int n_in,
                              void* d_out, int out_size, void* d_ws, size_t ws_size,
                              hipStream_t stream) {
    const float* cls_prop    = (const float*)d_in[0];
    const float* gt_classes  = (const float*)d_in[1];
    const float* prop_boxes  = (const float*)d_in[2];
    const float* gt_boxes    = (const float*)d_in[3];
    const float* prop_scores = (const float*)d_in[4];

    char* ws = (char*)d_ws;
    int*   order_g      = (int*)ws;                                   // B*N*4
    float* boxes_sorted = (float*)(ws + (size_t)BATCH * N * 4);       // B*N*16
    unsigned long long* mask =
        (unsigned long long*)(ws + (size_t)BATCH * N * 4 + (size_t)BATCH * N * 16);
    // mask: B*N*NW*8 = 4.36 MB; total ws use ~4.7 MB

    float* out_cls   = (float*)d_out;
    float* out_box   = out_cls + BATCH * MAXI;
    float* out_score = out_box + BATCH * MAXI * 4;

    k_rank<<<BATCH, 256, 0, stream>>>(gt_classes, prop_scores, gt_boxes,
                                      prop_boxes, order_g, boxes_sorted);
    dim3 g2(NW, NW, BATCH);
    k_mask<<<g2, 64, 0, stream>>>((const float4*)boxes_sorted, mask);
    k_scan<<<BATCH, 256, 0, stream>>>(mask, order_g, cls_prop, gt_classes,
                                      prop_boxes, gt_boxes, prop_scores,
                                      out_cls, out_box, out_score);
}

// Round 9
// 285.835 us; speedup vs baseline: 2.6796x; 2.6796x over previous
//
#include <hip/hip_runtime.h>
#include <stdint.h>

#pragma clang fp contract(off)

#define BATCH 8
#define G 64
#define P 2000
#define N 2064        // G + P
#define NW 33         // ceil(N/64) 64-bit words per mask row
#define MAXI 320
#define NMS_THR 0.3f

typedef unsigned long long u64;

// ---------------- Kernel 1: stable descending rank + scatter sorted boxes --
// grid (ceil(N/256), B). One element per thread. Replicates stable
// jnp.argsort(-scores): rank(i) = #{ j : s[j]>s[i] || (s[j]==s[i] && j<i) }.
__global__ __launch_bounds__(256) void k_rank(
    const float* __restrict__ gt_classes,
    const float* __restrict__ prop_scores,
    const float* __restrict__ gt_boxes,
    const float* __restrict__ prop_boxes,
    int* __restrict__ order_g,              // [B][N] sorted-pos -> orig idx
    float4* __restrict__ boxes_sorted)      // [B][N]
{
    __shared__ __align__(16) float s[N];
    const int b = blockIdx.y, tid = threadIdx.x;
    const int i = blockIdx.x * 256 + tid;

    for (int k = tid; k < N; k += 256)
        s[k] = (k < G) ? gt_classes[b * G + k] : prop_scores[b * P + (k - G)];
    __syncthreads();
    if (i >= N) return;

    const float my = s[i];
    int rank = 0;
    #pragma unroll 4
    for (int j = 0; j < N; j += 4) {
        // uniform address across lanes -> LDS broadcast, no bank conflicts
        const float4 v = *reinterpret_cast<const float4*>(&s[j]);
        rank += (int)((v.x > my) | ((v.x == my) & (j + 0 < i)));
        rank += (int)((v.y > my) | ((v.y == my) & (j + 1 < i)));
        rank += (int)((v.z > my) | ((v.z == my) & (j + 2 < i)));
        rank += (int)((v.w > my) | ((v.w == my) & (j + 3 < i)));
    }

    order_g[b * N + rank] = i;
    const float* src = (i < G) ? &gt_boxes[(size_t)(b * G + i) * 4]
                               : &prop_boxes[(size_t)(b * P + (i - G)) * 4];
    boxes_sorted[(size_t)b * N + rank] = *reinterpret_cast<const float4*>(src);
}

// ---------------- Kernel 2: suppression bitmask (transposed layout) -------
// grid (NW, NW, B), 64 threads. mask_t[b][w][i]: bit jj set iff sorted col
// j = w*64+jj > i and IoU(i,j) > thr. Only upper triangle (cb>=rb) written;
// k_scan never reads the lower triangle.
__global__ __launch_bounds__(64) void k_mask(
    const float4* __restrict__ boxes_sorted,
    u64* __restrict__ mask_t)               // [B][NW][N]
{
    const int rb = blockIdx.x, cb = blockIdx.y, b = blockIdx.z;
    if (cb < rb) return;                    // never read -> don't write
    const int t = threadIdx.x;
    const int i = rb * 64 + t;

    __shared__ float4 cbox[64];
    const int j0 = cb * 64;
    if (j0 + t < N) cbox[t] = boxes_sorted[(size_t)b * N + j0 + t];
    __syncthreads();
    if (i >= N) return;

    const float4 a = boxes_sorted[(size_t)b * N + i];
    const float areaA = (a.z - a.x) * (a.w - a.y);

    u64 bits = 0ull;
    const int jmax = min(64, N - j0);
    for (int jj = 0; jj < jmax; ++jj) {
        const int j = j0 + jj;
        if (j <= i) continue;
        const float4 c = cbox[jj];
        const float areaB = (c.z - c.x) * (c.w - c.y);
        const float xx1 = fmaxf(a.x, c.x), yy1 = fmaxf(a.y, c.y);
        const float xx2 = fminf(a.z, c.z), yy2 = fminf(a.w, c.w);
        const float inter = fmaxf(xx2 - xx1, 0.0f) * fmaxf(yy2 - yy1, 0.0f);
        const float uni = areaA + areaB - inter;
        const float iou = inter / fmaxf(uni, 1e-9f);
        if (iou > NMS_THR) bits |= 1ull << jj;
    }
    // coalesced: consecutive t -> consecutive 8B
    mask_t[((size_t)b * NW + cb) * N + i] = bits;
}

// ---------------- Kernel 3: greedy scan + select + write ------------------
// One block (256 thr) per image. Wave 0 runs the serial greedy scan with a
// lane-replicated current-chunk removal word (register-only inner loop);
// waves 1-3 double-buffer-stage the next chunk global->LDS.
__global__ __launch_bounds__(256) void k_scan(
    const u64* __restrict__ mask_t,
    const int* __restrict__ order_g,
    const float* __restrict__ cls_prop,
    const float* __restrict__ gt_classes,
    const float* __restrict__ prop_boxes,
    const float* __restrict__ gt_boxes,
    const float* __restrict__ prop_scores,
    float* __restrict__ out_cls, float* __restrict__ out_box,
    float* __restrict__ out_score)
{
    __shared__ u64 buf[2][NW][65];          // padded: 34.3 KB
    __shared__ u64 keep_words[NW];
    __shared__ unsigned char keep_orig[N];
    __shared__ int partial[256];
    __shared__ int excl[256];
    __shared__ int total;

    const int b = blockIdx.x, tid = threadIdx.x;
    const int lane = tid & 63, wave = tid >> 6;

    // stage chunk 0 (rows 0..63, words 0..NW-1) with all threads
    for (int k = tid; k < NW * 64; k += 256) {
        const int w = k >> 6, r = k & 63;
        buf[0][w][r] = mask_t[((size_t)b * NW + w) * N + r];
    }
    __syncthreads();

    u64 remv = 0ull;    // wave0 lane w (<NW): accumulated suppression word w
    for (int c = 0; c < NW; ++c) {
        const int cb_ = c & 1;
        if (wave > 0) {
            // stage chunk c+1 into the other buffer (192 threads)
            const int cn = c + 1;
            if (cn < NW) {
                const int nw = NW - cn;     // only words w>=cn are ever read
                for (int k = tid - 64; k < nw * 64; k += 192) {
                    const int w = cn + (k >> 6), r = k & 63;
                    const int i = cn * 64 + r;
                    buf[cb_ ^ 1][w][r] =
                        (i < N) ? mask_t[((size_t)b * NW + w) * N + i] : 0ull;
                }
            }
        } else {
            // ---- wave0: serial greedy over the 64 rows of chunk c ----
            u64 cur;    // removal state of current chunk's rows, replicated
            {
                const unsigned int lo = __shfl((unsigned int)remv, c, 64);
                const unsigned int hi = __shfl((unsigned int)(remv >> 32), c, 64);
                cur = ((u64)hi << 32) | lo;
            }
            u64 keepw = 0ull;
            const int rmax = min(64, N - c * 64);
            for (int r0 = 0; r0 < rmax; r0 += 8) {
                // prefetch 8 diag words (uniform addr -> broadcast reads)
                const u64 d0 = buf[cb_][c][r0 + 0], d1 = buf[cb_][c][r0 + 1];
                const u64 d2 = buf[cb_][c][r0 + 2], d3 = buf[cb_][c][r0 + 3];
                const u64 d4 = buf[cb_][c][r0 + 4], d5 = buf[cb_][c][r0 + 5];
                const u64 d6 = buf[cb_][c][r0 + 6], d7 = buf[cb_][c][r0 + 7];
                #define STEP(K, DK)                                           \
                    { const int r = r0 + K;                                   \
                      if (r < rmax && !((cur >> r) & 1ull)) {                 \
                          keepw |= 1ull << r; cur |= (DK); } }
                STEP(0, d0) STEP(1, d1) STEP(2, d2) STEP(3, d3)
                STEP(4, d4) STEP(5, d5) STEP(6, d6) STEP(7, d7)
                #undef STEP
            }
            // fold kept rows' suppression into future words (off the chain)
            if (lane > c && lane < NW) {
                u64 kw = keepw;
                while (kw) {
                    const int r = __builtin_ctzll(kw);
                    kw &= kw - 1;
                    remv |= buf[cb_][lane][r];
                }
            }
            if (lane == 0) keep_words[c] = keepw;
        }
        __syncthreads();
    }

    // scatter keep bits back to original index order
    for (int i = tid; i < N; i += 256) {
        const int o = order_g[b * N + i];
        keep_orig[o] = (unsigned char)((keep_words[i >> 6] >> (i & 63)) & 1ull);
    }
    __syncthreads();

    // block prefix sum over keep_orig
    const int SEG = (N + 255) / 256;   // 9
    const int s0 = tid * SEG;
    int sum = 0;
    for (int k = 0; k < SEG; ++k) {
        const int n = s0 + k;
        if (n < N) sum += keep_orig[n];
    }
    partial[tid] = sum;
    __syncthreads();
    if (tid == 0) {
        int run = 0;
        for (int t = 0; t < 256; ++t) { excl[t] = run; run += partial[t]; }
        total = run;
    }
    __syncthreads();

    int run = excl[tid];
    for (int k = 0; k < SEG; ++k) {
        const int n = s0 + k;
        if (n < N && keep_orig[n]) {
            const int pos = run++;
            if (pos < MAXI) {
                float cls, sc; float4 bx;
                if (n < G) {
                    cls = gt_classes[b * G + n];
                    sc  = cls;   // score_all uses gt_classes for first G
                    bx  = *reinterpret_cast<const float4*>(&gt_boxes[(size_t)(b * G + n) * 4]);
                } else {
                    const int q = n - G;
                    cls = cls_prop[b * P + q];
                    sc  = prop_scores[b * P + q];
                    bx  = *reinterpret_cast<const float4*>(&prop_boxes[(size_t)(b * P + q) * 4]);
                }
                out_cls[b * MAXI + pos] = cls;
                out_score[b * MAXI + pos] = sc;
                *reinterpret_cast<float4*>(&out_box[(size_t)(b * MAXI + pos) * 4]) = bx;
            }
        }
    }
    __syncthreads();

    // zero the invalid tail (harness poisons d_out before timed replays)
    const int cnt = min(total, MAXI);
    for (int k = cnt + tid; k < MAXI; k += 256) {
        out_cls[b * MAXI + k] = 0.0f;
        out_score[b * MAXI + k] = 0.0f;
        *reinterpret_cast<float4*>(&out_box[(size_t)(b * MAXI + k) * 4]) =
            make_float4(0.0f, 0.0f, 0.0f, 0.0f);
    }
}

extern "C" void kernel_launch(void* const* d_in, const int* in_sizes, int n_in,
                              void* d_out, int out_size, void* d_ws, size_t ws_size,
                              hipStream_t stream) {
    const float* cls_prop    = (const float*)d_in[0];
    const float* gt_classes  = (const float*)d_in[1];
    const float* prop_boxes  = (const float*)d_in[2];
    const float* gt_boxes    = (const float*)d_in[3];
    const float* prop_scores = (const float*)d_in[4];

    char* ws = (char*)d_ws;
    int*    order_g      = (int*)ws;                                  // B*N*4
    float4* boxes_sorted = (float4*)(ws + (size_t)BATCH * N * 4);     // B*N*16
    u64*    mask_t       = (u64*)(ws + (size_t)BATCH * N * 4
                                     + (size_t)BATCH * N * 16);       // B*NW*N*8 = 4.36 MB

    float* out_cls   = (float*)d_out;
    float* out_box   = out_cls + BATCH * MAXI;
    float* out_score = out_box + BATCH * MAXI * 4;

    dim3 g1((N + 255) / 256, BATCH);
    k_rank<<<g1, 256, 0, stream>>>(gt_classes, prop_scores, gt_boxes,
                                   prop_boxes, order_g, boxes_sorted);
    dim3 g2(NW, NW, BATCH);
    k_mask<<<g2, 64, 0, stream>>>((const float4*)boxes_sorted, mask_t);
    k_scan<<<BATCH, 256, 0, stream>>>(mask_t, order_g, cls_prop, gt_classes,
                                      prop_boxes, gt_boxes, prop_scores,
                                      out_cls, out_box, out_score);
}

// Round 20
// 265.651 us; speedup vs baseline: 2.8832x; 1.0760x over previous
//
#include <hip/hip_runtime.h>
#include <stdint.h>

#pragma clang fp contract(off)

#define BATCH 8
#define G 64
#define P 2000
#define N 2064        // G + P
#define NW 33         // ceil(N/64) 64-bit words per mask row
#define MAXI 320
#define NMS_THR 0.3f

typedef unsigned long long u64;

// ---------------- Kernel 1: stable descending rank + scatter sorted boxes --
// grid (ceil(N/256), B). One element per thread. Replicates stable
// jnp.argsort(-scores): rank(i) = #{ j : s[j]>s[i] || (s[j]==s[i] && j<i) }.
__global__ __launch_bounds__(256) void k_rank(
    const float* __restrict__ gt_classes,
    const float* __restrict__ prop_scores,
    const float* __restrict__ gt_boxes,
    const float* __restrict__ prop_boxes,
    int* __restrict__ order_g,              // [B][N] sorted-pos -> orig idx
    float4* __restrict__ boxes_sorted)      // [B][N]
{
    __shared__ __align__(16) float s[N];
    const int b = blockIdx.y, tid = threadIdx.x;
    const int i = blockIdx.x * 256 + tid;

    for (int k = tid; k < N; k += 256)
        s[k] = (k < G) ? gt_classes[b * G + k] : prop_scores[b * P + (k - G)];
    __syncthreads();
    if (i >= N) return;

    const float my = s[i];
    int rank = 0;
    #pragma unroll 4
    for (int j = 0; j < N; j += 4) {
        // uniform address across lanes -> LDS broadcast, no bank conflicts
        const float4 v = *reinterpret_cast<const float4*>(&s[j]);
        rank += (int)((v.x > my) | ((v.x == my) & (j + 0 < i)));
        rank += (int)((v.y > my) | ((v.y == my) & (j + 1 < i)));
        rank += (int)((v.z > my) | ((v.z == my) & (j + 2 < i)));
        rank += (int)((v.w > my) | ((v.w == my) & (j + 3 < i)));
    }

    order_g[b * N + rank] = i;
    const float* src = (i < G) ? &gt_boxes[(size_t)(b * G + i) * 4]
                               : &prop_boxes[(size_t)(b * P + (i - G)) * 4];
    boxes_sorted[(size_t)b * N + rank] = *reinterpret_cast<const float4*>(src);
}

// ---------------- Kernel 2: suppression bitmask (transposed layout) -------
// grid (NW, NW, B), 64 threads. mask_t[b][w][i]: bit jj set iff sorted col
// j = w*64+jj > i and IoU(i,j) > thr. Only upper triangle (cb>=rb) written;
// k_scan never reads the lower triangle.
__global__ __launch_bounds__(64) void k_mask(
    const float4* __restrict__ boxes_sorted,
    u64* __restrict__ mask_t)               // [B][NW][N]
{
    const int rb = blockIdx.x, cb = blockIdx.y, b = blockIdx.z;
    if (cb < rb) return;                    // never read -> don't write
    const int t = threadIdx.x;
    const int i = rb * 64 + t;

    __shared__ float4 cbox[64];
    const int j0 = cb * 64;
    if (j0 + t < N) cbox[t] = boxes_sorted[(size_t)b * N + j0 + t];
    __syncthreads();
    if (i >= N) return;

    const float4 a = boxes_sorted[(size_t)b * N + i];
    const float areaA = (a.z - a.x) * (a.w - a.y);

    u64 bits = 0ull;
    const int jmax = min(64, N - j0);
    for (int jj = 0; jj < jmax; ++jj) {
        const int j = j0 + jj;
        if (j <= i) continue;
        const float4 c = cbox[jj];
        const float areaB = (c.z - c.x) * (c.w - c.y);
        const float xx1 = fmaxf(a.x, c.x), yy1 = fmaxf(a.y, c.y);
        const float xx2 = fminf(a.z, c.z), yy2 = fminf(a.w, c.w);
        const float inter = fmaxf(xx2 - xx1, 0.0f) * fmaxf(yy2 - yy1, 0.0f);
        const float uni = areaA + areaB - inter;
        const float iou = inter / fmaxf(uni, 1e-9f);
        if (iou > NMS_THR) bits |= 1ull << jj;
    }
    // coalesced: consecutive t -> consecutive 8B
    mask_t[((size_t)b * NW + cb) * N + i] = bits;
}

// ---------------- Kernel 3: greedy scan + select + write ------------------
// One block (256 thr) per image. Wave 0 runs the serial greedy scan (diag
// word via per-lane register + shfl broadcast -> no LDS latency on the
// chain); waves 1-3 double-buffer-stage the next chunk with batch-issued
// loads (registers first, LDS writes after -> one pipelined vmcnt wait).
__global__ __launch_bounds__(256) void k_scan(
    const u64* __restrict__ mask_t,
    const int* __restrict__ order_g,
    const float* __restrict__ cls_prop,
    const float* __restrict__ gt_classes,
    const float* __restrict__ prop_boxes,
    const float* __restrict__ gt_boxes,
    const float* __restrict__ prop_scores,
    float* __restrict__ out_cls, float* __restrict__ out_box,
    float* __restrict__ out_score)
{
    __shared__ u64 buf[2][NW][65];          // padded: 34.3 KB
    __shared__ u64 keep_words[NW];
    __shared__ unsigned char keep_orig[N];
    __shared__ int partial[256];
    __shared__ int excl[256];
    __shared__ int total;

    const int b = blockIdx.x, tid = threadIdx.x;
    const int lane = tid & 63, wave = tid >> 6;

    // stage chunk 0 (rows 0..63, words 0..NW-1) with all threads
    for (int k = tid; k < NW * 64; k += 256) {
        const int w = k >> 6, r = k & 63;
        buf[0][w][r] = mask_t[((size_t)b * NW + w) * N + r];
    }
    __syncthreads();

    u64 remv = 0ull;    // wave0 lane w (<NW): accumulated suppression word w
    for (int c = 0; c < NW; ++c) {
        const int cb_ = c & 1;
        if (wave > 0) {
            // stage chunk c+1: batch-issue global loads into registers
            // (static indices -> stays in VGPRs), then write LDS. One
            // pipelined vmcnt drain instead of 11 serial load->ds_write.
            const int cn = c + 1;
            if (cn < NW) {
                const int nw = NW - cn;     // only words w>=cn are ever read
                const int tot = nw * 64;
                u64 tmp[11];
                #pragma unroll
                for (int t = 0; t < 11; ++t) {
                    const int k = (tid - 64) + t * 192;
                    if (k < tot) {
                        const int w = cn + (k >> 6), r = k & 63;
                        tmp[t] = mask_t[((size_t)b * NW + w) * N + cn * 64 + r];
                    }
                }
                #pragma unroll
                for (int t = 0; t < 11; ++t) {
                    const int k = (tid - 64) + t * 192;
                    if (k < tot) {
                        const int w = cn + (k >> 6), r = k & 63;
                        buf[cb_ ^ 1][w][r] = tmp[t];
                    }
                }
            }
        } else {
            // ---- wave0: serial greedy over the 64 rows of chunk c ----
            u64 cur;    // removal state of current chunk's rows, replicated
            {
                const unsigned int lo = __shfl((unsigned int)remv, c, 64);
                const unsigned int hi = __shfl((unsigned int)(remv >> 32), c, 64);
                cur = ((u64)hi << 32) | lo;
            }
            // lane r owns diag word of row r; broadcast per step via shfl
            // (constant lane index after unroll -> readlane, no LDS stall)
            const u64 myD = buf[cb_][c][lane];
            const unsigned int dlo = (unsigned int)myD;
            const unsigned int dhi = (unsigned int)(myD >> 32);
            u64 keepw = 0ull;
            const int rmax = min(64, N - c * 64);
            #pragma unroll
            for (int r = 0; r < 64; ++r) {
                const unsigned int l = __shfl(dlo, r, 64);
                const unsigned int h = __shfl(dhi, r, 64);
                const u64 dr = ((u64)h << 32) | l;
                if (r < rmax && !((cur >> r) & 1ull)) {
                    keepw |= 1ull << r;
                    cur |= dr;
                }
            }
            // fold kept rows' suppression into future words, 4 LDS reads
            // issued per round (independent -> one lgkmcnt wait per 4)
            if (lane > c && lane < NW) {
                u64 kw = keepw;
                while (kw) {
                    const int r0 = __builtin_ctzll(kw); kw &= kw - 1;
                    int r1 = -1, r2 = -1, r3 = -1;
                    if (kw) { r1 = __builtin_ctzll(kw); kw &= kw - 1; }
                    if (kw) { r2 = __builtin_ctzll(kw); kw &= kw - 1; }
                    if (kw) { r3 = __builtin_ctzll(kw); kw &= kw - 1; }
                    const u64 v0 = buf[cb_][lane][r0];
                    const u64 v1 = buf[cb_][lane][r1 < 0 ? r0 : r1];
                    const u64 v2 = buf[cb_][lane][r2 < 0 ? r0 : r2];
                    const u64 v3 = buf[cb_][lane][r3 < 0 ? r0 : r3];
                    remv |= v0;
                    if (r1 >= 0) remv |= v1;
                    if (r2 >= 0) remv |= v2;
                    if (r3 >= 0) remv |= v3;
                }
            }
            if (lane == 0) keep_words[c] = keepw;
        }
        __syncthreads();
    }

    // scatter keep bits back to original index order
    for (int i = tid; i < N; i += 256) {
        const int o = order_g[b * N + i];
        keep_orig[o] = (unsigned char)((keep_words[i >> 6] >> (i & 63)) & 1ull);
    }
    __syncthreads();

    // block prefix sum over keep_orig
    const int SEG = (N + 255) / 256;   // 9
    const int s0 = tid * SEG;
    int sum = 0;
    for (int k = 0; k < SEG; ++k) {
        const int n = s0 + k;
        if (n < N) sum += keep_orig[n];
    }
    partial[tid] = sum;
    __syncthreads();
    if (tid == 0) {
        int run = 0;
        for (int t = 0; t < 256; ++t) { excl[t] = run; run += partial[t]; }
        total = run;
    }
    __syncthreads();

    int run = excl[tid];
    for (int k = 0; k < SEG; ++k) {
        const int n = s0 + k;
        if (n < N && keep_orig[n]) {
            const int pos = run++;
            if (pos < MAXI) {
                float cls, sc; float4 bx;
                if (n < G) {
                    cls = gt_classes[b * G + n];
                    sc  = cls;   // score_all uses gt_classes for first G
                    bx  = *reinterpret_cast<const float4*>(&gt_boxes[(size_t)(b * G + n) * 4]);
                } else {
                    const int q = n - G;
                    cls = cls_prop[b * P + q];
                    sc  = prop_scores[b * P + q];
                    bx  = *reinterpret_cast<const float4*>(&prop_boxes[(size_t)(b * P + q) * 4]);
                }
                out_cls[b * MAXI + pos] = cls;
                out_score[b * MAXI + pos] = sc;
                *reinterpret_cast<float4*>(&out_box[(size_t)(b * MAXI + pos) * 4]) = bx;
            }
        }
    }
    __syncthreads();

    // zero the invalid tail (harness poisons d_out before timed replays)
    const int cnt = min(total, MAXI);
    for (int k = cnt + tid; k < MAXI; k += 256) {
        out_cls[b * MAXI + k] = 0.0f;
        out_score[b * MAXI + k] = 0.0f;
        *reinterpret_cast<float4*>(&out_box[(size_t)(b * MAXI + k) * 4]) =
            make_float4(0.0f, 0.0f, 0.0f, 0.0f);
    }
}

extern "C" void kernel_launch(void* const* d_in, const int* in_sizes, int n_in,
                              void* d_out, int out_size, void* d_ws, size_t ws_size,
                              hipStream_t stream) {
    const float* cls_prop    = (const float*)d_in[0];
    const float* gt_classes  = (const float*)d_in[1];
    const float* prop_boxes  = (const float*)d_in[2];
    const float* gt_boxes    = (const float*)d_in[3];
    const float* prop_scores = (const float*)d_in[4];

    char* ws = (char*)d_ws;
    int*    order_g      = (int*)ws;                                  // B*N*4
    float4* boxes_sorted = (float4*)(ws + (size_t)BATCH * N * 4);     // B*N*16
    u64*    mask_t       = (u64*)(ws + (size_t)BATCH * N * 4
                                     + (size_t)BATCH * N * 16);       // B*NW*N*8 = 4.36 MB

    float* out_cls   = (float*)d_out;
    float* out_box   = out_cls + BATCH * MAXI;
    float* out_score = out_box + BATCH * MAXI * 4;

    dim3 g1((N + 255) / 256, BATCH);
    k_rank<<<g1, 256, 0, stream>>>(gt_classes, prop_scores, gt_boxes,
                                   prop_boxes, order_g, boxes_sorted);
    dim3 g2(NW, NW, BATCH);
    k_mask<<<g2, 64, 0, stream>>>((const float4*)boxes_sorted, mask_t);
    k_scan<<<BATCH, 256, 0, stream>>>(mask_t, order_g, cls_prop, gt_classes,
                                      prop_boxes, gt_boxes, prop_scores,
                                      out_cls, out_box, out_score);
}